// Round 2
// baseline (931.750 us; speedup 1.0000x reference)
//
#include <hip/hip_runtime.h>

#define N 512
#define DIM_IN 256
#define DQ 64
#define EDGE_DIM 64
#define EPS 1e-8f

// ---------------------------------------------------------------------------
// Kernel 1: edge_scores[e] = edge_attr[e,:] . We + be
// ---------------------------------------------------------------------------
__global__ void edge_scores_kernel(const float* __restrict__ edge_attr,
                                   const float* __restrict__ We,
                                   const float* __restrict__ be,
                                   float* __restrict__ scores, int E) {
    int e = blockIdx.x * blockDim.x + threadIdx.x;
    if (e >= E) return;
    float acc = be[0];
    const float4* ea = (const float4*)(edge_attr + (size_t)e * EDGE_DIM);
    const float4* w4 = (const float4*)We;
    #pragma unroll
    for (int j = 0; j < EDGE_DIM / 4; ++j) {
        float4 a = ea[j];
        float4 w = w4[j];
        acc += a.x * w.x + a.y * w.y + a.z * w.z + a.w * w.w;
    }
    scores[e] = acc;
}

// ---------------------------------------------------------------------------
// Kernel 2: c[u,v] = (edge_path[u,v,:] . scores) / (sum(edge_path[u,v,:]) + eps)
// One 64-lane wave per (u,v) pair. E = 512 -> 128 float4 -> 2 float4/lane.
// This is the HBM-bound kernel (536 MB stream).
// ---------------------------------------------------------------------------
__global__ void __launch_bounds__(256) path_c_kernel(
    const float* __restrict__ edge_path,   // [N*N*E]
    const float* __restrict__ scores,      // [E]
    float* __restrict__ c) {
    size_t pair = (size_t)((blockIdx.x * blockDim.x + threadIdx.x) >> 6);
    int lane = threadIdx.x & 63;
    if (pair >= (size_t)N * N) return;
    const float4* p4 = (const float4*)(edge_path + pair * 512);
    const float4* s4 = (const float4*)scores;
    float num = 0.f, den = 0.f;
    #pragma unroll
    for (int it = 0; it < 2; ++it) {
        int idx = lane + it * 64;
        float4 pv = p4[idx];
        float4 sv = s4[idx];
        num += pv.x * sv.x + pv.y * sv.y + pv.z * sv.z + pv.w * sv.w;
        den += pv.x + pv.y + pv.z + pv.w;
    }
    #pragma unroll
    for (int off = 32; off >= 1; off >>= 1) {
        num += __shfl_down(num, off, 64);
        den += __shfl_down(den, off, 64);
    }
    if (lane == 0) c[pair] = num / (den + EPS);
}

// ---------------------------------------------------------------------------
// Kernel 3: q/k/v projections. One thread per output element.
// which = gid / (N*DQ): 0->q, 1->k, 2->v
// ---------------------------------------------------------------------------
__global__ void qkv_kernel(const float* __restrict__ query,
                           const float* __restrict__ key,
                           const float* __restrict__ value,
                           const float* __restrict__ Wq, const float* __restrict__ bq,
                           const float* __restrict__ Wk, const float* __restrict__ bk,
                           const float* __restrict__ Wv, const float* __restrict__ bv,
                           float* __restrict__ q, float* __restrict__ k,
                           float* __restrict__ v) {
    int gid = blockIdx.x * blockDim.x + threadIdx.x;
    int which = gid / (N * DQ);
    int rem = gid - which * (N * DQ);
    int row = rem / DQ, col = rem - row * DQ;
    const float* X; const float* W; const float* bb; float* out;
    if (which == 0)      { X = query; W = Wq; bb = bq; out = q; }
    else if (which == 1) { X = key;   W = Wk; bb = bk; out = k; }
    else                 { X = value; W = Wv; bb = bv; out = v; }
    float acc = bb[col];
    const float* xr = X + (size_t)row * DIM_IN;
    for (int j = 0; j < DIM_IN; ++j)
        acc = fmaf(xr[j], W[(size_t)j * DQ + col], acc);
    out[rem] = acc;
}

// ---------------------------------------------------------------------------
// Kernel 4: fused attention row. One block (256 thr) per row u.
// a[v] = (q[u].k[v]/8 + b[u,v] + c[u,v]) * mask(u,v); softmax; out = a @ v
// ---------------------------------------------------------------------------
__global__ void __launch_bounds__(256) attn_kernel(
    const float* __restrict__ q, const float* __restrict__ k,
    const float* __restrict__ v, const float* __restrict__ b,
    const float* __restrict__ c, const int* __restrict__ ptr, int nptr,
    float* __restrict__ out) {
    int u = blockIdx.x;
    int t = threadIdx.x;
    __shared__ float qs[DQ];
    __shared__ float a_s[N];
    __shared__ float red[4];
    __shared__ float part[256];

    if (t < DQ) qs[t] = q[(size_t)u * DQ + t];
    __syncthreads();

    // segment of u: count of ptr[1..nptr-1] <= u  (searchsorted side='right')
    int segu = 0;
    for (int g = 1; g < nptr; ++g) segu += (ptr[g] <= u) ? 1 : 0;

    const float scale = 0.125f;  // 1/sqrt(64)
    for (int vi = t; vi < N; vi += 256) {
        const float4* k4 = (const float4*)(k + (size_t)vi * DQ);
        const float4* q4 = (const float4*)qs;
        float acc = 0.f;
        #pragma unroll
        for (int j = 0; j < DQ / 4; ++j) {
            float4 kk = k4[j]; float4 qq = q4[j];
            acc += kk.x * qq.x + kk.y * qq.y + kk.z * qq.z + kk.w * qq.w;
        }
        int segv = 0;
        for (int g = 1; g < nptr; ++g) segv += (ptr[g] <= vi) ? 1 : 0;
        float mask = (segu == segv) ? 1.f : 0.f;
        a_s[vi] = (acc * scale + b[(size_t)u * N + vi] + c[(size_t)u * N + vi]) * mask;
    }
    __syncthreads();

    // block max
    float m = -1e30f;
    for (int vi = t; vi < N; vi += 256) m = fmaxf(m, a_s[vi]);
    #pragma unroll
    for (int off = 32; off >= 1; off >>= 1) m = fmaxf(m, __shfl_xor(m, off, 64));
    int wid = t >> 6;
    if ((t & 63) == 0) red[wid] = m;
    __syncthreads();
    m = fmaxf(fmaxf(red[0], red[1]), fmaxf(red[2], red[3]));
    __syncthreads();   // all reads of red done before overwrite

    // exp + block sum
    float s = 0.f;
    for (int vi = t; vi < N; vi += 256) {
        float e = __expf(a_s[vi] - m);
        a_s[vi] = e;
        s += e;
    }
    #pragma unroll
    for (int off = 32; off >= 1; off >>= 1) s += __shfl_xor(s, off, 64);
    if ((t & 63) == 0) red[wid] = s;
    __syncthreads();   // covers a_s writes + red writes
    float inv = 1.f / (red[0] + red[1] + red[2] + red[3]);

    // out[u, col] = inv * sum_v a_s[v] * v[v, col]; 4 v-chunks of 128
    int col = t & 63;
    int chunk = t >> 6;
    float acc = 0.f;
    const float* vbase = v + (size_t)chunk * 128 * DQ + col;
    #pragma unroll 4
    for (int vi = 0; vi < 128; ++vi)
        acc = fmaf(a_s[chunk * 128 + vi], vbase[(size_t)vi * DQ], acc);
    part[t] = acc;
    __syncthreads();
    if (t < 64) {
        float tot = part[t] + part[t + 64] + part[t + 128] + part[t + 192];
        out[(size_t)u * DQ + t] = tot * inv;
    }
}

// ---------------------------------------------------------------------------
extern "C" void kernel_launch(void* const* d_in, const int* in_sizes, int n_in,
                              void* d_out, int out_size, void* d_ws, size_t ws_size,
                              hipStream_t stream) {
    const float* query     = (const float*)d_in[0];
    const float* key       = (const float*)d_in[1];
    const float* value     = (const float*)d_in[2];
    const float* edge_attr = (const float*)d_in[3];
    const float* b         = (const float*)d_in[4];
    const float* edge_path = (const float*)d_in[5];
    // d_in[6] node_path: result discarded by reference -> never read
    const int*   ptr       = (const int*)d_in[7];
    const float* We        = (const float*)d_in[8];
    const float* be        = (const float*)d_in[9];
    // d_in[10] Wn, d_in[11] bn: feed only the discarded node encoding
    const float* Wq = (const float*)d_in[12];
    const float* bq = (const float*)d_in[13];
    const float* Wk = (const float*)d_in[14];
    const float* bk = (const float*)d_in[15];
    const float* Wv = (const float*)d_in[16];
    const float* bv = (const float*)d_in[17];
    float* out = (float*)d_out;
    int nptr = in_sizes[7];
    const int E = 512;

    char* ws = (char*)d_ws;
    float* c_buf  = (float*)(ws);                         // N*N  = 1 MiB
    float* q_buf  = (float*)(ws + (size_t)N * N * 4);     // 128 KiB
    float* k_buf  = (float*)(ws + (size_t)N * N * 4 + 131072);
    float* v_buf  = (float*)(ws + (size_t)N * N * 4 + 2 * 131072);
    float* scores = (float*)(ws + (size_t)N * N * 4 + 3 * 131072);

    edge_scores_kernel<<<(E + 255) / 256, 256, 0, stream>>>(edge_attr, We, be, scores, E);
    qkv_kernel<<<(3 * N * DQ) / 256, 256, 0, stream>>>(
        query, key, value, Wq, bq, Wk, bk, Wv, bv, q_buf, k_buf, v_buf);
    // one wave per (u,v): N*N waves, 4 waves/block
    path_c_kernel<<<(N * N) / 4, 256, 0, stream>>>(edge_path, scores, c_buf);
    attn_kernel<<<N, 256, 0, stream>>>(q_buf, k_buf, v_buf, b, c_buf, ptr, nptr, out);
}